// Round 6
// baseline (668.687 us; speedup 1.0000x reference)
//
#include <hip/hip_runtime.h>
#include <cstdint>
#include <cstddef>

#define T_STEPS 20
#define B_SZ 128
#define H_SZ 256
#define E_SZ 128
#define C_SZ 512
#define V_SZ 32000
#define G3H 768

typedef __bf16 bf16x8 __attribute__((ext_vector_type(8)));
typedef float f32x4 __attribute__((ext_vector_type(4)));
typedef unsigned short u16x8 __attribute__((ext_vector_type(8)));

#define AS1 __attribute__((address_space(1)))
#define AS3 __attribute__((address_space(3)))

__device__ __forceinline__ unsigned short f2bf(float f) {
  unsigned int u = __builtin_bit_cast(unsigned int, f);
  u += 0x7fffu + ((u >> 16) & 1u);   // round-to-nearest-even
  return (unsigned short)(u >> 16);
}

// bounded spin until *p >= 16 (agent scope). Bounded so a pathological
// scheduling failure shows up as wrong output, not a harness hang.
// SLEEP must be a compile-time constant (s_sleep takes a literal imm).
template <int SLEEP>
__device__ __forceinline__ void wait16(int* p) {
  for (int i = 0; i < 4000000; ++i) {
    if (__hip_atomic_load(p, __ATOMIC_RELAXED, __HIP_MEMORY_SCOPE_AGENT) >= 16) return;
    __builtin_amdgcn_s_sleep(SLEEP);
  }
}

// ---------- K00: zero the sync counters + ticket pool (re-run every call) ----------
__global__ void k_zero(int* __restrict__ c) {
  if (threadIdx.x < 64) c[threadIdx.x] = 0;
}

// ---------- K0: prep (r3 version) — Whh (i,g,o; f-gate dead) -> bf16 swizzled; h0 -> hsb slot 0 ----------
// whh_bs: [l][tt(16)][n(48)][k(256)] bf16; n: 0-15=i,16-31=g,32-47=o for h-cols tt*16+(n&15)
//         element (n,k) holds Whh[row(n)][k ^ ((n&7)<<3)]
// hsb:    [l][slot(21)][b(128)][k(256)] bf16, element (b,k) holds h[b][k ^ ((b&7)<<3)]
__global__ __launch_bounds__(256) void k_prep(const float* __restrict__ Whh_p,
    const float* __restrict__ Whh_n, const float* __restrict__ h1, const float* __restrict__ h2,
    unsigned short* __restrict__ whh_bs, unsigned short* __restrict__ hsb) {
  const int idx = blockIdx.x * 256 + threadIdx.x;
  const int NW = 2 * 16 * 48 * 256;
  if (idx < NW) {
    const int k = idx & 255;
    const int n = (idx >> 8) % 48;
    const int tt = ((idx >> 8) / 48) & 15;
    const int l = idx / (16 * 48 * 256);
    const int gate = n >> 4;
    const int c = n & 15;
    const int row = (gate == 0 ? 0 : (gate == 1 ? 512 : 768)) + tt * 16 + c;
    const int ksrc = (k & 7) | (((k >> 3) ^ (n & 7)) << 3);
    const float* W = l ? Whh_n : Whh_p;
    whh_bs[idx] = f2bf(W[(size_t)row * 256 + ksrc]);
  } else {
    const int i2 = idx - NW;          // [2][128][256]
    const int k = i2 & 255;
    const int b = (i2 >> 8) & 127;
    const int l = i2 >> 15;
    const int ksrc = (k & 7) | (((k >> 3) ^ (b & 7)) << 3);
    const float* h = l ? h2 : h1;     // [1,256] broadcast row
    hsb[(size_t)(l * 21) * 32768 + (size_t)b * 256 + k] = f2bf(h[ksrc]);
  }
}

// ---------- K1a: ctxg[l,b,g] = context[b,:] @ Wih_l[row(g),128:640] + bih + bhh ----------
__global__ __launch_bounds__(256) void k_ctx_gemm(const float* __restrict__ context,
    const float* __restrict__ Wih_p, const float* __restrict__ Wih_n,
    const float* __restrict__ bih_p, const float* __restrict__ bhh_p,
    const float* __restrict__ bih_n, const float* __restrict__ bhh_n,
    float* __restrict__ ctxg) {
  const int bid = blockIdx.x;          // 96 blocks: l(2) x btile(16) x gtile(3)
  const int l = bid / 48;
  const int bt = (bid / 3) & 15;
  const int gt = bid % 3;
  const int b0 = bt * 8;
  const int g = gt * 256 + threadIdx.x;        // compact col in [0,768)
  const int row = g + (gt > 0 ? 256 : 0);      // skip dead f-gate rows [256,512)
  __shared__ float csh[8][C_SZ];
  for (int i = threadIdx.x; i < 8 * C_SZ; i += 256)
    csh[i >> 9][i & 511] = context[(size_t)(b0 + (i >> 9)) * C_SZ + (i & 511)];
  __syncthreads();
  const float* W = (l ? Wih_n : Wih_p) + (size_t)row * 640 + E_SZ;
  float acc[8] = {};
  for (int c = 0; c < C_SZ; c += 4) {
    const float4 w = *(const float4*)(W + c);
#pragma unroll
    for (int bb = 0; bb < 8; ++bb) {
      const float4 h = *(const float4*)(&csh[bb][c]);
      acc[bb] += w.x * h.x + w.y * h.y + w.z * h.z + w.w * h.w;
    }
  }
  const float bias = l ? (bih_n[row] + bhh_n[row]) : (bih_p[row] + bhh_p[row]);
#pragma unroll
  for (int bb = 0; bb < 8; ++bb)
    ctxg[((size_t)l * B_SZ + b0 + bb) * G3H + g] = acc[bb] + bias;
}

// ---------- K1b: xg[l,r,g] = input_l[r,:] @ Wih_l[row(g),0:128] + ctxg[l, r&127, g] ----------
__global__ __launch_bounds__(256) void k_in_gemm(const float* __restrict__ inP,
    const float* __restrict__ inN,
    const float* __restrict__ Wih_p, const float* __restrict__ Wih_n,
    const float* __restrict__ ctxg, float* __restrict__ xg) {
  const int bid = blockIdx.x;          // 960 blocks: l(2) x rowtile(160) x gtile(3)
  const int l = bid / 480;
  const int rest = bid % 480;
  const int rt = rest / 3;
  const int gt = rest % 3;
  const int r0 = rt * 16;
  const int g = gt * 256 + threadIdx.x;
  const int row = g + (gt > 0 ? 256 : 0);
  __shared__ float ish[16][E_SZ];
  const float* inp = l ? inN : inP;
  for (int i = threadIdx.x; i < 16 * E_SZ; i += 256)
    ish[i >> 7][i & 127] = inp[(size_t)(r0 + (i >> 7)) * E_SZ + (i & 127)];
  __syncthreads();
  const float* W = (l ? Wih_n : Wih_p) + (size_t)row * 640;
  float acc[16] = {};
  for (int k = 0; k < E_SZ; k += 4) {
    const float4 w = *(const float4*)(W + k);
#pragma unroll
    for (int rr = 0; rr < 16; ++rr) {
      const float4 h = *(const float4*)(&ish[rr][k]);
      acc[rr] += w.x * h.x + w.y * h.y + w.z * h.z + w.w * h.w;
    }
  }
#pragma unroll
  for (int rr = 0; rr < 16; ++rr) {
    const int b = (r0 + rr) & 127;
    const float cv = ctxg[((size_t)l * B_SZ + b) * G3H + g];
    xg[((size_t)l * (T_STEPS * B_SZ) + r0 + rr) * G3H + g] = acc[rr] + cv;
  }
}

// ---------- K2: MEGA — steps (blocks 0-31, r3 structure) OVERLAPPED with projection ----------
// 256 blocks x 256 thr, 114.7 KB LDS -> exactly 1 block/CU, all co-resident.
// Steps worker (l,tt): owns h-cols [tt*16,tt*16+16), per step releases cnt[l*20+t] (agent).
// Proj workers: pull 64-col vocab strips from ticket pool, process slabs t-ascending,
// gated on cnt[l*20+t]==16 (bounded spin + acquire fence per new t). Steps workers join
// the pool when done. out = hs_bf16[5120,256] @ Wp[32000,256]^T + bp, NT stores.
__global__ __launch_bounds__(256, 1) void k_mega(const unsigned short* __restrict__ whh_bs,
    const float* __restrict__ xg, unsigned short* __restrict__ hsb,
    const float* __restrict__ Wp, const float* __restrict__ bias, float* __restrict__ out,
    int* __restrict__ cnt) {
  __shared__ __align__(16) unsigned char lds[114688];
  __shared__ int tkt_s;
  const int tid = threadIdx.x;
  const int lane = tid & 63;
  const int wave = tid >> 6;

  if (blockIdx.x < 32) {
    // ================= steps role (r3 structure) =================
    unsigned short* wls = (unsigned short*)lds;              // 24 KB Whh panel (resident)
    unsigned short* hls = (unsigned short*)(lds + 24576);    // 64 KB h(t)
    float* xls = (float*)(lds + 90112);                      // 24 KB xg slice
    const int l = blockIdx.x >> 4;
    const int tt = blockIdx.x & 15;
    {
      const unsigned short* wsrc = whh_bs + (size_t)(l * 16 + tt) * 12288 + tid * 8;
#pragma unroll
      for (int i = 0; i < 6; ++i)
        __builtin_amdgcn_global_load_lds((const AS1 void*)(wsrc + i * 2048),
                                         (AS3 void*)(wls + tid * 8 + i * 2048), 16, 0, 0);
    }
    for (int t = 0; t < T_STEPS; ++t) {
      const unsigned short* hsrc = hsb + (size_t)(l * 21 + t) * 32768 + tid * 8;
#pragma unroll
      for (int i = 0; i < 16; ++i)
        __builtin_amdgcn_global_load_lds((const AS1 void*)(hsrc + i * 2048),
                                         (AS3 void*)(hls + tid * 8 + i * 2048), 16, 0, 0);
      const size_t xgbase = ((size_t)(l * T_STEPS + t) * B_SZ) * G3H;
#pragma unroll
      for (int i = 0; i < 6; ++i) {
        const int q = tid + i * 256;            // 16B chunk index, 1536 total
        const int b = q / 12;
        const int r = q - b * 12;
        const int gate = r >> 2;
        const int cg = r & 3;
        const float* src = xg + xgbase + (size_t)b * G3H + gate * 256 + tt * 16 + cg * 4;
        __builtin_amdgcn_global_load_lds((const AS1 void*)src,
                                         (AS3 void*)((char*)xls + q * 16), 16, 0, 0);
      }
      asm volatile("s_waitcnt vmcnt(0)" ::: "memory");
      __builtin_amdgcn_s_barrier();

      f32x4 acc[2][3] = {};
#pragma unroll
      for (int kf = 0; kf < 8; ++kf) {
        const int ch = kf * 4 + (lane >> 4);
        bf16x8 bf[3];
#pragma unroll
        for (int nt = 0; nt < 3; ++nt) {
          const int n = nt * 16 + (lane & 15);
          bf[nt] = __builtin_bit_cast(bf16x8, *(const u16x8*)(wls + n * 256 + ((ch ^ (n & 7)) << 3)));
        }
#pragma unroll
        for (int m = 0; m < 2; ++m) {
          const int b = wave * 32 + m * 16 + (lane & 15);
          const bf16x8 af = __builtin_bit_cast(bf16x8, *(const u16x8*)(hls + b * 256 + ((ch ^ (b & 7)) << 3)));
#pragma unroll
          for (int nt = 0; nt < 3; ++nt)
            acc[m][nt] = __builtin_amdgcn_mfma_f32_16x16x32_bf16(af, bf[nt], acc[m][nt], 0, 0, 0);
        }
      }

      unsigned short* hout = hsb + (size_t)(l * 21 + 1 + t) * 32768;
#pragma unroll
      for (int m = 0; m < 2; ++m) {
#pragma unroll
        for (int i = 0; i < 4; ++i) {
          const int b = wave * 32 + m * 16 + (lane >> 4) * 4 + i;
          const int col = lane & 15;
          const float gi = xls[(b * 3 + 0) * 16 + col] + acc[m][0][i];
          const float gg = xls[(b * 3 + 1) * 16 + col] + acc[m][1][i];
          const float go = xls[(b * 3 + 2) * 16 + col] + acc[m][2][i];
          const float cc = (1.0f / (1.0f + expf(-gi))) * tanhf(gg);
          const float h = (1.0f / (1.0f + expf(-go))) * tanhf(cc);
          const int jc = tt * 16 + col;
          const int kpos = (jc & 7) | (((jc >> 3) ^ (b & 7)) << 3);
          hout[(size_t)b * 256 + kpos] = f2bf(h);
        }
      }

      // release h(t); wait for all 16 producers of this lstm (except after last step)
      asm volatile("s_waitcnt vmcnt(0)" ::: "memory");
      __syncthreads();
      if (tid == 0)
        __hip_atomic_fetch_add(&cnt[l * T_STEPS + t], 1, __ATOMIC_RELEASE, __HIP_MEMORY_SCOPE_AGENT);
      if (t < T_STEPS - 1) {
        if (tid == 0) wait16<1>(&cnt[l * T_STEPS + t]);
        __syncthreads();
        __builtin_amdgcn_fence(__ATOMIC_ACQUIRE, "agent");
      }
    }
  }

  // ================= proj role (all blocks; steps workers join when done) =================
  unsigned short* smem = (unsigned short*)lds;   // 3 x 16 KB A triple-buffer
  const int wgrp = wave >> 1;
  const int wc = wave & 1;
  const int lr = wgrp * 16 + (lane & 15);
  int seen0 = -1, seen1 = -1;                    // last t acquired, per lstm

  for (;;) {
    __syncthreads();                             // LDS handoff + ticket broadcast
    if (tid == 0)
      tkt_s = __hip_atomic_fetch_add(&cnt[63], 1, __ATOMIC_RELAXED, __HIP_MEMORY_SCOPE_AGENT);
    __syncthreads();
    const int strip = tkt_s;
    if (strip >= 500) break;
    const int n_base = strip * 64 + wc * 32;

    // B panel (Wp f32 -> bf16 frags in registers)
    bf16x8 bfr[2][8];
#pragma unroll
    for (int nt = 0; nt < 2; ++nt) {
      const int n_g = n_base + nt * 16 + (lane & 15);
      const float* src = Wp + (size_t)n_g * 256 + (lane >> 4) * 8;
#pragma unroll
      for (int kf = 0; kf < 8; ++kf) {
        const float4 a = *(const float4*)(src + kf * 32);
        const float4 b = *(const float4*)(src + kf * 32 + 4);
        u16x8 u;
        u[0] = f2bf(a.x); u[1] = f2bf(a.y); u[2] = f2bf(a.z); u[3] = f2bf(a.w);
        u[4] = f2bf(b.x); u[5] = f2bf(b.y); u[6] = f2bf(b.z); u[7] = f2bf(b.w);
        bfr[nt][kf] = __builtin_bit_cast(bf16x8, u);
      }
    }
    const float bv0 = bias[n_base + (lane & 15)];
    const float bv1 = bias[n_base + 16 + (lane & 15)];

    // slab order j: t ascending, then l, then quarter q. it = l*80+t*4+q addresses output.
#define ENSURE(J)                                                                          \
    {                                                                                      \
      const int t_ = (J) >> 3, l_ = ((J) >> 2) & 1;                                        \
      int& s_ = l_ ? seen1 : seen0;                                                        \
      if (t_ > s_) {                                                                       \
        wait16<16>(&cnt[l_ * T_STEPS + t_]);                                               \
        __builtin_amdgcn_fence(__ATOMIC_ACQUIRE, "agent");                                 \
        s_ = t_;                                                                           \
      }                                                                                    \
    }
#define STAGE_A(J, BUF)                                                                    \
    {                                                                                      \
      const int t_ = (J) >> 3, l_ = ((J) >> 2) & 1, q_ = (J) & 3;                          \
      const unsigned short* src_ = hsb + (size_t)(l_ * 21 + 1 + t_) * 32768 + q_ * 8192 + tid * 8; \
      unsigned short* dst_ = smem + (BUF) * 8192 + tid * 8;                                \
      _Pragma("unroll")                                                                    \
      for (int i_ = 0; i_ < 4; ++i_)                                                       \
        __builtin_amdgcn_global_load_lds((const AS1 void*)(src_ + i_ * 2048),              \
                                         (AS3 void*)(dst_ + i_ * 2048), 16, 0, 0);         \
    }

    ENSURE(0); STAGE_A(0, 0);
    ENSURE(1); STAGE_A(1, 1);
    for (int j = 0; j < 160; ++j) {
      __builtin_amdgcn_s_barrier();
      if (j + 2 < 160) { ENSURE(j + 2); STAGE_A(j + 2, (j + 2) % 3); }
      if (j == 0) { asm volatile("s_waitcnt vmcnt(8)" ::: "memory"); }
      else        { asm volatile("s_waitcnt vmcnt(16)" ::: "memory"); }
      __builtin_amdgcn_s_barrier();
      const unsigned short* sA = smem + (j % 3) * 8192;
      f32x4 acc0 = {}, acc1 = {};
#pragma unroll
      for (int kf = 0; kf < 8; ++kf) {
        const int ch = (kf * 4 + (lane >> 4)) ^ (lr & 7);
        const bf16x8 af = __builtin_bit_cast(bf16x8, *(const u16x8*)(sA + lr * 256 + (ch << 3)));
        acc0 = __builtin_amdgcn_mfma_f32_16x16x32_bf16(af, bfr[0][kf], acc0, 0, 0, 0);
        acc1 = __builtin_amdgcn_mfma_f32_16x16x32_bf16(af, bfr[1][kf], acc1, 0, 0, 0);
      }
      const int t_ = j >> 3, l_ = (j >> 2) & 1, q_ = j & 3;
      const int it = l_ * 80 + t_ * 4 + q_;
      const size_t row0 = (size_t)it * 32 + wgrp * 16 + (lane >> 4) * 4;
      float* o0 = out + row0 * V_SZ + n_base + (lane & 15);
#pragma unroll
      for (int i = 0; i < 4; ++i) {
        __builtin_nontemporal_store(acc0[i] + bv0, &o0[(size_t)i * V_SZ]);
        __builtin_nontemporal_store(acc1[i] + bv1, &o0[(size_t)i * V_SZ + 16]);
      }
    }
#undef ENSURE
#undef STAGE_A
  }
}

extern "C" void kernel_launch(void* const* d_in, const int* in_sizes, int n_in,
                              void* d_out, int out_size, void* d_ws, size_t ws_size,
                              hipStream_t stream) {
  (void)in_sizes; (void)n_in; (void)out_size; (void)ws_size;
  const float* inputPrev = (const float*)d_in[0];
  const float* inputNext = (const float*)d_in[1];
  const float* context   = (const float*)d_in[2];
  const float* hidden1   = (const float*)d_in[3];
  const float* hidden2   = (const float*)d_in[4];
  const float* Wih_p = (const float*)d_in[5];
  const float* Whh_p = (const float*)d_in[6];
  const float* bih_p = (const float*)d_in[7];
  const float* bhh_p = (const float*)d_in[8];
  const float* Wih_n = (const float*)d_in[9];
  const float* Whh_n = (const float*)d_in[10];
  const float* bih_n = (const float*)d_in[11];
  const float* bhh_n = (const float*)d_in[12];
  const float* Wp = (const float*)d_in[13];
  const float* bp = (const float*)d_in[14];
  float* out = (float*)d_out;

  // workspace carve (16B-aligned); total ~20.1 MB
  char* ws = (char*)d_ws;
  float* xg_all        = (float*)(ws + 0);                   // [2][20][128][768] f32 = 15,728,640
  float* ctxg          = (float*)(ws + 15728640);            // [2][128][768] f32     =    786,432
  unsigned short* hsb  = (unsigned short*)(ws + 16515072);   // [2][21][128][256] bf16 swz = 2,752,512
  unsigned short* whhb = (unsigned short*)(ws + 19267584);   // [2][16][48][256] bf16 swz  =   786,432
  int* cnt             = (int*)(ws + 20054016);              // 64 ints: 40 step flags + ticket @63

  k_zero<<<1, 64, 0, stream>>>(cnt);
  k_prep<<<1792, 256, 0, stream>>>(Whh_p, Whh_n, hidden1, hidden2, whhb, hsb);
  k_ctx_gemm<<<96, 256, 0, stream>>>(context, Wih_p, Wih_n, bih_p, bhh_p, bih_n, bhh_n, ctxg);
  k_in_gemm<<<960, 256, 0, stream>>>(inputPrev, inputNext, Wih_p, Wih_n, ctxg, xg_all);
  k_mega<<<256, 256, 0, stream>>>(whhb, xg_all, hsb, Wp, bp, out, cnt);
}